// Round 12
// baseline (456.093 us; speedup 1.0000x reference)
//
#include <hip/hip_runtime.h>
#include <hip/hip_cooperative_groups.h>
#include <math.h>

namespace cg = cooperative_groups;

#define ALPHA 0.2f
#define LOG2E 1.44269504089f

typedef __attribute__((ext_vector_type(8))) short bf16x8;
typedef __attribute__((ext_vector_type(4))) float f32x4;

__device__ __forceinline__ float elu1(float x)  { return x > 0.f ? x : (__expf(x) - 1.f); }

// round-to-nearest-even f32 -> bf16 (finite values only)
__device__ __forceinline__ unsigned short f2bf(float x) {
    unsigned u = __float_as_uint(x);
    return (unsigned short)((u + 0x7fffu + ((u >> 16) & 1u)) >> 16);
}
__device__ __forceinline__ unsigned pkbf16(float a, float b) {
    return (unsigned)f2bf(a) | ((unsigned)f2bf(b) << 16);
}
__device__ __forceinline__ float bfs(unsigned short v) { return __uint_as_float((unsigned)v << 16); }
// round-half-up pack (a->lo, b->hi) via single v_perm on bias-added bits
__device__ __forceinline__ unsigned pkbf_rhu(float a, float b) {
    unsigned ua = __float_as_uint(a) + 0x8000u;
    unsigned ub = __float_as_uint(b) + 0x8000u;
    return __builtin_amdgcn_perm(ub, ua, 0x07060302u);
}

// ---------------------------------------------------------------------------
// P0: vb 0..287 -> weight transpose tiles (z<8: Wh K=256; z==8: Wo K=1024);
//     vb 288..2335 -> x f32->bf16 (1024 elems each).
// ---------------------------------------------------------------------------
__device__ void phase_prep(char* smem, int vb,
    const float* __restrict__ x, const float* __restrict__ Wh,
    const float* __restrict__ Wo, unsigned short* __restrict__ xb,
    unsigned short* __restrict__ WhT, unsigned short* __restrict__ WoT)
{
    const int tid = threadIdx.x;

    if (vb >= 288) {                  // x convert
        int idx = (vb - 288) * 1024 + tid * 4;
        float4 v = *(const float4*)(x + idx);
        uint2 o = make_uint2(pkbf16(v.x, v.y), pkbf16(v.z, v.w));
        *(uint2*)(xb + idx) = o;
        return;
    }

    const int z = vb >> 5, rem = vb & 31;
    const int bx = rem & 15, by = rem >> 4;
    const int K = (z < 8) ? 256 : 1024;
    if (bx * 64 >= K) return;
    const float* in = (z < 8) ? (Wh + (size_t)z * K * 128) : Wo;
    unsigned short* out = (z < 8) ? (WhT + (size_t)z * 128 * K) : WoT;
    const int k0 = bx * 64, n0 = by * 64;

    float (*T)[65] = (float(*)[65])smem;

    const int kr = tid >> 4, nc = (tid & 15) * 4;
#pragma unroll
    for (int s = 0; s < 4; ++s) {
        float4 v = *(const float4*)(in + (size_t)(k0 + kr + s * 16) * 128 + n0 + nc);
        T[kr + s * 16][nc]     = v.x;
        T[kr + s * 16][nc + 1] = v.y;
        T[kr + s * 16][nc + 2] = v.z;
        T[kr + s * 16][nc + 3] = v.w;
    }
    __syncthreads();
    const int nr0 = tid >> 3, kc = (tid & 7) * 8;
#pragma unroll
    for (int s = 0; s < 2; ++s) {
        int nr = nr0 + s * 32;
        unsigned pk[4];
#pragma unroll
        for (int q = 0; q < 4; ++q)
            pk[q] = pkbf16(T[kc + 2 * q][nr], T[kc + 2 * q + 1][nr]);
        *(uint4*)(out + (size_t)(n0 + nr) * K + k0 + kc) = make_uint4(pk[0], pk[1], pk[2], pk[3]);
    }
}

// ---------------------------------------------------------------------------
// GEMM phase: BM=64, BN=128, WM=32, WN=64, DOF (fused f1/f2). C^T via aliased
// LDS -> coalesced stores. A bf16 [M][K], Bt bf16 [n][K], Ct bf16 [n][8192].
// ---------------------------------------------------------------------------
__device__ void phase_gemm(char* smem, int bx, int by,
    const unsigned short* __restrict__ A, const unsigned short* __restrict__ Bt,
    unsigned short* __restrict__ Ct, int K,
    const float* __restrict__ aV, float* __restrict__ f1g, float* __restrict__ f2g)
{
    const int BM = 64, BN = 128, WM = 32, WN = 64;
    const int RM = WM / 16, RN = WN / 16;
    const int NCA = BM * 8 / 256, NCB = BN * 8 / 256;
    unsigned short (*As)[72] = (unsigned short(*)[72])smem;
    unsigned short (*Bs)[72] = (unsigned short(*)[72])(smem + BM * 72 * 2);
    unsigned short (*Cs)[72] = (unsigned short(*)[72])smem;          // alias, BM+8=72
    float* redf = (float*)(smem + BN * 72 * 2);

    const int tid = threadIdx.x;
    const int w = tid >> 6, lane = tid & 63;
    const int n16 = lane & 15, quad = lane >> 4;
    const int wm = (w & 1) * WM, wn = (w >> 1) * WN;
    const int m0 = bx * BM, n0 = by * BN;

    f32x4 acc[RM][RN];
#pragma unroll
    for (int mm = 0; mm < RM; ++mm)
#pragma unroll
        for (int nn = 0; nn < RN; ++nn) acc[mm][nn] = (f32x4){0.f, 0.f, 0.f, 0.f};

    uint4 ra[NCA], rb[NCB];
#pragma unroll
    for (int i = 0; i < NCA; ++i) {
        int c = tid * NCA + i, r = c >> 3, cc = (c & 7) * 8;
        ra[i] = *(const uint4*)(A + (size_t)(m0 + r) * K + cc);
    }
#pragma unroll
    for (int i = 0; i < NCB; ++i) {
        int c = tid * NCB + i, r = c >> 3, cc = (c & 7) * 8;
        rb[i] = *(const uint4*)(Bt + (size_t)(n0 + r) * K + cc);
    }

    const int nk = K >> 6;
    for (int kt = 0; kt < nk; ++kt) {
        __syncthreads();
#pragma unroll
        for (int i = 0; i < NCA; ++i) {
            int c = tid * NCA + i, r = c >> 3, cc = (c & 7) * 8;
            *(uint4*)&As[r][cc] = ra[i];
        }
#pragma unroll
        for (int i = 0; i < NCB; ++i) {
            int c = tid * NCB + i, r = c >> 3, cc = (c & 7) * 8;
            *(uint4*)&Bs[r][cc] = rb[i];
        }
        __syncthreads();
        if (kt + 1 < nk) {
            int k0 = (kt + 1) * 64;
#pragma unroll
            for (int i = 0; i < NCA; ++i) {
                int c = tid * NCA + i, r = c >> 3, cc = (c & 7) * 8;
                ra[i] = *(const uint4*)(A + (size_t)(m0 + r) * K + k0 + cc);
            }
#pragma unroll
            for (int i = 0; i < NCB; ++i) {
                int c = tid * NCB + i, r = c >> 3, cc = (c & 7) * 8;
                rb[i] = *(const uint4*)(Bt + (size_t)(n0 + r) * K + k0 + cc);
            }
        }
#pragma unroll
        for (int ks = 0; ks < 2; ++ks) {
            bf16x8 am[RM], bn[RN];
#pragma unroll
            for (int mm = 0; mm < RM; ++mm)
                am[mm] = *(const bf16x8*)&As[wm + mm * 16 + n16][ks * 32 + quad * 8];
#pragma unroll
            for (int nn = 0; nn < RN; ++nn)
                bn[nn] = *(const bf16x8*)&Bs[wn + nn * 16 + n16][ks * 32 + quad * 8];
#pragma unroll
            for (int mm = 0; mm < RM; ++mm)
#pragma unroll
                for (int nn = 0; nn < RN; ++nn)
                    acc[mm][nn] = __builtin_amdgcn_mfma_f32_16x16x32_bf16(
                        am[mm], bn[nn], acc[mm][nn], 0, 0, 0);
        }
    }

    __syncthreads();   // all LDS frag reads done before Cs aliases As/Bs

#pragma unroll
    for (int nn = 0; nn < RN; ++nn) {
        int n = wn + nn * 16 + n16;
#pragma unroll
        for (int mm = 0; mm < RM; ++mm) {
            int m = wm + mm * 16 + quad * 4;
            f32x4 a = acc[mm][nn];
            ushort4 o = make_ushort4(f2bf(a[0]), f2bf(a[1]), f2bf(a[2]), f2bf(a[3]));
            *(ushort4*)&Cs[n][m] = o;
        }
    }
    __syncthreads();

    // coalesced C^T store: row n = 64 shorts contiguous
    const int CHUNKS = 8, RPP = 32;
    const int row = tid / CHUNKS, ch = tid % CHUNKS;
#pragma unroll
    for (int s = 0; s < BN / RPP; ++s) {
        int n = row + s * RPP;
        *(uint4*)(Ct + (size_t)(n0 + n) * 8192 + m0 + ch * 8) =
            *(const uint4*)&Cs[n][ch * 8];
    }

    // fused f1/f2 (one head resident: BN==128)
    {
        const int mloc = tid & 63, fq = tid >> 6;
        const float* az = aV + by * 256;
        float s1 = 0.f, s2 = 0.f;
#pragma unroll 8
        for (int k = 0; k < 32; ++k) {
            int f = fq * 32 + k;
            float h = bfs(Cs[f][mloc]);
            s1 += h * az[f];
            s2 += h * az[128 + f];
        }
        *(float2*)&redf[(fq * 64 + mloc) * 2] = make_float2(s1, s2);
        __syncthreads();
        if (tid < 64) {
            float a1 = redf[tid * 2]       + redf[(64 + tid) * 2]
                     + redf[(128 + tid) * 2] + redf[(192 + tid) * 2];
            float a2 = redf[tid * 2 + 1]       + redf[(64 + tid) * 2 + 1]
                     + redf[(128 + tid) * 2 + 1] + redf[(192 + tid) * 2 + 1];
            f1g[(size_t)by * 8192 + m0 + tid] = a1;
            f2g[(size_t)by * 8192 + m0 + tid] = a2;
        }
        __syncthreads();   // redf/Cs free before next virtual block
    }
}

// ---------------------------------------------------------------------------
// Attention phase (R9-verified body): exp-free p = max(Ai*u, A2i*v),
// double-buffered JT=64 LDS tiles, lsum via ones-column MFMA.
// ---------------------------------------------------------------------------
template <int NI, int OUTBF>
__device__ void phase_attn(char* smem, int hy, int ibx, int bz,
    const unsigned short* __restrict__ hT, const float* __restrict__ f1g,
    const float* __restrict__ f2g, float* __restrict__ outf,
    unsigned short* __restrict__ outb, int elu2)
{
    const int N = 1024, JT = 64, JP = 72;
    unsigned short (*hls)[128][JP] = (unsigned short(*)[128][JP])smem;
    float* ul = (float*)(smem + 2 * 128 * JP * 2);   // 36864
    float* vl = ul + 1024;
    float* wred = vl + 1024;

    const int tid = threadIdx.x;
    const int w = tid >> 6, lane = tid & 63;
    const int n16 = lane & 15, quad = lane >> 4;
    const int hb = hy * 8 + bz;
    const int ITILE = 64 * NI;
    const int iw0 = ibx * ITILE + w * (16 * NI);

    // u/v tables + block max of f2L
    {
        int j4 = tid * 4;
        float4 fv = *(const float4*)(f2g + (size_t)hb * N + j4);
        fv.x *= LOG2E; fv.y *= LOG2E; fv.z *= LOG2E; fv.w *= LOG2E;
        float m4 = fmaxf(fmaxf(fv.x, fv.y), fmaxf(fv.z, fv.w));
#pragma unroll
        for (int off = 32; off; off >>= 1) m4 = fmaxf(m4, __shfl_xor(m4, off));
        if (lane == 0) wred[w] = m4;
        float4 uu, vv;
        uu.x = __builtin_amdgcn_exp2f(fv.x); vv.x = __builtin_amdgcn_exp2f(ALPHA * fv.x);
        uu.y = __builtin_amdgcn_exp2f(fv.y); vv.y = __builtin_amdgcn_exp2f(ALPHA * fv.y);
        uu.z = __builtin_amdgcn_exp2f(fv.z); vv.z = __builtin_amdgcn_exp2f(ALPHA * fv.z);
        uu.w = __builtin_amdgcn_exp2f(fv.w); vv.w = __builtin_amdgcn_exp2f(ALPHA * fv.w);
        *(float4*)&ul[j4] = uu;
        *(float4*)&vl[j4] = vv;
    }

    float f1L[NI];
#pragma unroll
    for (int ii = 0; ii < NI; ++ii)
        f1L[ii] = f1g[(size_t)hb * N + iw0 + ii * 16 + n16] * LOG2E;

    const unsigned short* gsrc = hT + (size_t)hy * 128 * 8192 + bz * 1024;
    const int sf = tid >> 3, sj = (tid & 7) * 8;

    bf16x8 stg[4];
#pragma unroll
    for (int s = 0; s < 4; ++s)
        stg[s] = *(const bf16x8*)(gsrc + (size_t)(sf + 32 * s) * 8192 + sj);

    __syncthreads();   // ul/vl/wred visible
    const float f2mL = fmaxf(fmaxf(wred[0], wred[1]), fmaxf(wred[2], wred[3]));
    float Ai[NI], A2i[NI];
#pragma unroll
    for (int ii = 0; ii < NI; ++ii) {
        float s = f1L[ii] + f2mL;
        float mc = fmaxf(s, ALPHA * s);
        Ai[ii]  = __builtin_amdgcn_exp2f(f1L[ii] - mc);
        A2i[ii] = __builtin_amdgcn_exp2f(ALPHA * f1L[ii] - mc);
    }

    f32x4 acc[NI][8], accl[NI];
#pragma unroll
    for (int ii = 0; ii < NI; ++ii) {
        accl[ii] = (f32x4){0.f, 0.f, 0.f, 0.f};
#pragma unroll
        for (int t = 0; t < 8; ++t) acc[ii][t] = (f32x4){0.f, 0.f, 0.f, 0.f};
    }
    bf16x8 ones;
    { union { bf16x8 v; unsigned u[4]; } o;
      o.u[0] = o.u[1] = o.u[2] = o.u[3] = 0x3F803F80u; ones = o.v; }

    // stage tile 0 into buf 0
#pragma unroll
    for (int s = 0; s < 4; ++s)
        *(bf16x8*)&hls[0][sf + 32 * s][sj] = stg[s];
    __syncthreads();

    for (int jt = 0; jt < N / JT; ++jt) {
        const int cur = jt & 1;
        if (jt + 1 < N / JT) {
            int j0n = (jt + 1) * JT;
#pragma unroll
            for (int s = 0; s < 4; ++s)
                stg[s] = *(const bf16x8*)(gsrc + (size_t)(sf + 32 * s) * 8192 + j0n + sj);
        }
        const int j0 = jt * JT;
#pragma unroll
        for (int kk = 0; kk < 2; ++kk) {
            const int jb = j0 + kk * 32 + quad * 8;
            float4 u0 = *(const float4*)&ul[jb], u1 = *(const float4*)&ul[jb + 4];
            float4 v0 = *(const float4*)&vl[jb], v1 = *(const float4*)&vl[jb + 4];
            float uj[8] = {u0.x, u0.y, u0.z, u0.w, u1.x, u1.y, u1.z, u1.w};
            float vj[8] = {v0.x, v0.y, v0.z, v0.w, v1.x, v1.y, v1.z, v1.w};

            bf16x8 afr[NI];
#pragma unroll
            for (int ii = 0; ii < NI; ++ii) {
                union { bf16x8 v; unsigned u[4]; } cvt;
#pragma unroll
                for (int q = 0; q < 4; ++q) {
                    float p0 = fmaxf(Ai[ii] * uj[2 * q],     A2i[ii] * vj[2 * q]);
                    float p1 = fmaxf(Ai[ii] * uj[2 * q + 1], A2i[ii] * vj[2 * q + 1]);
                    cvt.u[q] = pkbf_rhu(p0, p1);
                }
                afr[ii] = cvt.v;
            }
#pragma unroll
            for (int t = 0; t < 8; ++t) {
                bf16x8 bfr = *(const bf16x8*)&hls[cur][t * 16 + n16][kk * 32 + quad * 8];
#pragma unroll
                for (int ii = 0; ii < NI; ++ii)
                    acc[ii][t] = __builtin_amdgcn_mfma_f32_16x16x32_bf16(
                        afr[ii], bfr, acc[ii][t], 0, 0, 0);
            }
#pragma unroll
            for (int ii = 0; ii < NI; ++ii)
                accl[ii] = __builtin_amdgcn_mfma_f32_16x16x32_bf16(
                    afr[ii], ones, accl[ii], 0, 0, 0);
        }
        if (jt + 1 < N / JT) {
#pragma unroll
            for (int s = 0; s < 4; ++s)
                *(bf16x8*)&hls[1 - cur][sf + 32 * s][sj] = stg[s];
        }
        __syncthreads();
    }

    // epilogue: C/D layout col=lane&15 (f), row=quad*4+reg (i); lsum in accl
#pragma unroll
    for (int ii = 0; ii < NI; ++ii) {
#pragma unroll
        for (int r = 0; r < 4; ++r) {
            float inv = 1.f / accl[ii][r];
            int i = iw0 + ii * 16 + quad * 4 + r;
#pragma unroll
            for (int t = 0; t < 8; ++t) {
                float tv = acc[ii][t][r] * inv;
                tv = elu1(tv);
                if (OUTBF) {
                    outb[(size_t)(bz * 1024 + i) * 1024 + hy * 128 + t * 16 + n16] = f2bf(tv);
                } else {
                    if (elu2) tv = elu1(tv);
                    outf[(size_t)(bz * 1024 + i) * 128 + t * 16 + n16] = tv;
                }
            }
        }
    }
}

// ---------------------------------------------------------------------------
// Megakernel: whole model in one cooperative launch, 256 blocks x 256 thr.
// Phases separated by device-scope fence + grid sync.
// ---------------------------------------------------------------------------
__global__ __launch_bounds__(256) void mega(
    const float* __restrict__ x, const float* __restrict__ Wh,
    const float* __restrict__ ah, const float* __restrict__ Wo,
    const float* __restrict__ ao,
    unsigned short* xb, unsigned short* WhT, unsigned short* WoT,
    unsigned short* h1T, unsigned short* xcb, unsigned short* h2T,
    float* f1a, float* f2a, float* f1b, float* f2b, float* out)
{
    __shared__ __align__(16) char SMEM[46080];
    cg::grid_group grid = cg::this_grid();
    const int bid = blockIdx.x;

    // P0: prep (288 weight tiles + 2048 x-convert chunks)
    for (int vb = bid; vb < 2336; vb += 256) {
        phase_prep(SMEM, vb, x, Wh, Wo, xb, WhT, WoT);
        __syncthreads();
    }
    __threadfence();
    grid.sync();

    // P1: GEMM L1 + f1/f2 (virtual grid 128 m-blocks x 8 heads)
    for (int vb = bid; vb < 1024; vb += 256) {
        phase_gemm(SMEM, vb >> 3, vb & 7, xb, WhT, h1T, 256, ah, f1a, f2a);
        __syncthreads();
    }
    __threadfence();
    grid.sync();

    // P2: attn L1 (virtual grid 8 hy x 8 ibx x 8 bz, NI=2)
    for (int vb = bid; vb < 512; vb += 256) {
        phase_attn<2, 1>(SMEM, vb & 7, (vb >> 3) & 7, vb >> 6,
                         h1T, f1a, f2a, nullptr, xcb, 0);
        __syncthreads();
    }
    __threadfence();
    grid.sync();

    // P3: GEMM L2 + f1/f2 (128 m-blocks, single 128-col tile)
    if (bid < 128) {
        phase_gemm(SMEM, bid, 0, xcb, WoT, h2T, 1024, ao, f1b, f2b);
    }
    __threadfence();
    grid.sync();

    // P4: attn L2 (virtual grid 8 bz x 16 ibx, NI=1)
    if (bid < 128) {
        phase_attn<1, 0>(SMEM, 0, bid >> 3, bid & 7,
                         h2T, f1b, f2b, out, nullptr, 1);
    }
}

// ---------------------------------------------------------------------------
// B=8, N=1024, D=256, H=8, F=128
// ---------------------------------------------------------------------------
extern "C" void kernel_launch(void* const* d_in, const int* in_sizes, int n_in,
                              void* d_out, int out_size, void* d_ws, size_t ws_size,
                              hipStream_t stream)
{
    const float* x  = (const float*)d_in[0];
    const float* Wh = (const float*)d_in[2];
    const float* ah = (const float*)d_in[3];
    const float* Wo = (const float*)d_in[4];
    const float* ao = (const float*)d_in[5];
    float* out = (float*)d_out;

    unsigned short* xb  = (unsigned short*)d_ws;       // [8192][256]
    unsigned short* WhT = xb + 2097152;                // [1024][256]
    unsigned short* WoT = WhT + 262144;                // [128][1024]
    unsigned short* h1T = WoT + 131072;                // [8][128][8192]
    unsigned short* xcb = h1T + 8388608;               // [8192][1024]
    unsigned short* h2T = xcb + 8388608;               // [128][8192]
    float* f1a  = (float*)(h2T + 1048576);             // [8][8192]
    float* f2a  = f1a + 65536;                         // [8][8192]
    float* f1b  = f2a + 65536;                         // [8192]
    float* f2b  = f1b + 8192;                          // [8192]

    void* args[] = {
        (void*)&x, (void*)&Wh, (void*)&ah, (void*)&Wo, (void*)&ao,
        (void*)&xb, (void*)&WhT, (void*)&WoT,
        (void*)&h1T, (void*)&xcb, (void*)&h2T,
        (void*)&f1a, (void*)&f2a, (void*)&f1b, (void*)&f2b, (void*)&out
    };
    hipLaunchCooperativeKernel((const void*)mega, dim3(256), dim3(256),
                               args, 0, stream);
}

// Round 13
// 179.510 us; speedup vs baseline: 2.5408x; 2.5408x over previous
//
#include <hip/hip_runtime.h>
#include <math.h>

#define ALPHA 0.2f
#define LOG2E 1.44269504089f

typedef __attribute__((ext_vector_type(8))) short bf16x8;
typedef __attribute__((ext_vector_type(4))) float f32x4;

__device__ __forceinline__ float elu1(float x)  { return x > 0.f ? x : (__expf(x) - 1.f); }

// round-to-nearest-even f32 -> bf16 (finite values only)
__device__ __forceinline__ unsigned short f2bf(float x) {
    unsigned u = __float_as_uint(x);
    return (unsigned short)((u + 0x7fffu + ((u >> 16) & 1u)) >> 16);
}
__device__ __forceinline__ unsigned pkbf16(float a, float b) {
    return (unsigned)f2bf(a) | ((unsigned)f2bf(b) << 16);
}
__device__ __forceinline__ float bflo(unsigned v) { return __uint_as_float(v << 16); }
__device__ __forceinline__ float bfhi(unsigned v) { return __uint_as_float(v & 0xffff0000u); }
__device__ __forceinline__ float bfs(unsigned short v) { return __uint_as_float((unsigned)v << 16); }
// round-half-up pack (a->lo, b->hi) via single v_perm on bias-added bits
__device__ __forceinline__ unsigned pkbf_rhu(float a, float b) {
    unsigned ua = __float_as_uint(a) + 0x8000u;
    unsigned ub = __float_as_uint(b) + 0x8000u;
    return __builtin_amdgcn_perm(ub, ua, 0x07060302u);
}

// ---------------------------------------------------------------------------
// Prep (single launch): W [z][K][128] f32 -> WT [z][128][K] bf16, LDS 64x64
// tile transpose. z<8: Wh (K=256); z==8: Wo (K=1024). grid (16, 2, 9).
// ---------------------------------------------------------------------------
__global__ __launch_bounds__(256) void cvt_w_all(
    const float* __restrict__ Wh, const float* __restrict__ Wo,
    unsigned short* __restrict__ WhT, unsigned short* __restrict__ WoT)
{
    const int z = blockIdx.z;
    const int K = (z < 8) ? 256 : 1024;
    if (blockIdx.x * 64 >= K) return;
    const float* in = (z < 8) ? (Wh + (size_t)z * K * 128) : Wo;
    unsigned short* out = (z < 8) ? (WhT + (size_t)z * 128 * K) : WoT;

    __shared__ float T[64][65];
    const int tid = threadIdx.x;
    const int k0 = blockIdx.x * 64, n0 = blockIdx.y * 64;

    const int kr = tid >> 4, nc = (tid & 15) * 4;
#pragma unroll
    for (int s = 0; s < 4; ++s) {
        float4 v = *(const float4*)(in + (size_t)(k0 + kr + s * 16) * 128 + n0 + nc);
        T[kr + s * 16][nc]     = v.x;
        T[kr + s * 16][nc + 1] = v.y;
        T[kr + s * 16][nc + 2] = v.z;
        T[kr + s * 16][nc + 3] = v.w;
    }
    __syncthreads();
    const int nr0 = tid >> 3, kc = (tid & 7) * 8;
#pragma unroll
    for (int s = 0; s < 2; ++s) {
        int nr = nr0 + s * 32;
        unsigned pk[4];
#pragma unroll
        for (int q = 0; q < 4; ++q)
            pk[q] = pkbf16(T[kc + 2 * q][nr], T[kc + 2 * q + 1][nr]);
        *(uint4*)(out + (size_t)(n0 + nr) * K + k0 + kc) = make_uint4(pk[0], pk[1], pk[2], pk[3]);
    }
}

// ---------------------------------------------------------------------------
// LDS-staged bf16 MFMA GEMM with transposed C store.
// AF32=1: A is f32 (x input), converted to bf16 during LDS staging.
// C^T staged via LDS aliased over As/Bs -> coalesced uint4 stores.
// DOF=1 (BN==128): fused f1/f2 head dot-products from resident C^T tile.
// ---------------------------------------------------------------------------
template <int BM, int BN, int WM, int WN, int DOF, int AF32>
__global__ __launch_bounds__(256) void gemm_t(
    const void* __restrict__ Avp, const unsigned short* __restrict__ Bt,
    unsigned short* __restrict__ Ct, int K,
    const float* __restrict__ aV, float* __restrict__ f1g, float* __restrict__ f2g)
{
    const int RM = WM / 16, RN = WN / 16;
    const int NCA = BM * 8 / 256, NCB = BN * 8 / 256;
    __shared__ __align__(16) unsigned short SAB[(BM + BN) * 72];
    unsigned short (*As)[72] = (unsigned short(*)[72])SAB;
    unsigned short (*Bs)[72] = (unsigned short(*)[72])(SAB + BM * 72);
    unsigned short (*Cs)[BM + 8] = (unsigned short(*)[BM + 8])SAB;   // alias
    float* redf = (float*)(SAB + BN * (BM + 8));                     // after Cs

    const int tid = threadIdx.x;
    const int w = tid >> 6, lane = tid & 63;
    const int n16 = lane & 15, quad = lane >> 4;
    const int WX = BM / WM;
    const int wm = (w % WX) * WM, wn = (w / WX) * WN;
    const int m0 = blockIdx.x * BM, n0 = blockIdx.y * BN;

    const float* Af = (const float*)Avp;
    const unsigned short* Ab = (const unsigned short*)Avp;
    const int ar = tid >> 2, akc = (tid & 3) * 16;

    f32x4 acc[RM][RN];
#pragma unroll
    for (int mm = 0; mm < RM; ++mm)
#pragma unroll
        for (int nn = 0; nn < RN; ++nn) acc[mm][nn] = (f32x4){0.f, 0.f, 0.f, 0.f};

    uint4 ra[NCA], rb[NCB];
    float4 raf[4];
    if (AF32) {
#pragma unroll
        for (int j = 0; j < 4; ++j)
            raf[j] = *(const float4*)(Af + (size_t)(m0 + ar) * K + akc + 4 * j);
    } else {
#pragma unroll
        for (int i = 0; i < NCA; ++i) {
            int c = tid * NCA + i, r = c >> 3, cc = (c & 7) * 8;
            ra[i] = *(const uint4*)(Ab + (size_t)(m0 + r) * K + cc);
        }
    }
#pragma unroll
    for (int i = 0; i < NCB; ++i) {
        int c = tid * NCB + i, r = c >> 3, cc = (c & 7) * 8;
        rb[i] = *(const uint4*)(Bt + (size_t)(n0 + r) * K + cc);
    }

    const int nk = K >> 6;
    for (int kt = 0; kt < nk; ++kt) {
        __syncthreads();
        if (AF32) {
            uint4 lo = make_uint4(pkbf16(raf[0].x, raf[0].y), pkbf16(raf[0].z, raf[0].w),
                                  pkbf16(raf[1].x, raf[1].y), pkbf16(raf[1].z, raf[1].w));
            uint4 hi = make_uint4(pkbf16(raf[2].x, raf[2].y), pkbf16(raf[2].z, raf[2].w),
                                  pkbf16(raf[3].x, raf[3].y), pkbf16(raf[3].z, raf[3].w));
            *(uint4*)&As[ar][akc]     = lo;
            *(uint4*)&As[ar][akc + 8] = hi;
        } else {
#pragma unroll
            for (int i = 0; i < NCA; ++i) {
                int c = tid * NCA + i, r = c >> 3, cc = (c & 7) * 8;
                *(uint4*)&As[r][cc] = ra[i];
            }
        }
#pragma unroll
        for (int i = 0; i < NCB; ++i) {
            int c = tid * NCB + i, r = c >> 3, cc = (c & 7) * 8;
            *(uint4*)&Bs[r][cc] = rb[i];
        }
        __syncthreads();
        if (kt + 1 < nk) {
            int k0 = (kt + 1) * 64;
            if (AF32) {
#pragma unroll
                for (int j = 0; j < 4; ++j)
                    raf[j] = *(const float4*)(Af + (size_t)(m0 + ar) * K + k0 + akc + 4 * j);
            } else {
#pragma unroll
                for (int i = 0; i < NCA; ++i) {
                    int c = tid * NCA + i, r = c >> 3, cc = (c & 7) * 8;
                    ra[i] = *(const uint4*)(Ab + (size_t)(m0 + r) * K + k0 + cc);
                }
            }
#pragma unroll
            for (int i = 0; i < NCB; ++i) {
                int c = tid * NCB + i, r = c >> 3, cc = (c & 7) * 8;
                rb[i] = *(const uint4*)(Bt + (size_t)(n0 + r) * K + k0 + cc);
            }
        }
#pragma unroll
        for (int ks = 0; ks < 2; ++ks) {
            bf16x8 am[RM], bn[RN];
#pragma unroll
            for (int mm = 0; mm < RM; ++mm)
                am[mm] = *(const bf16x8*)&As[wm + mm * 16 + n16][ks * 32 + quad * 8];
#pragma unroll
            for (int nn = 0; nn < RN; ++nn)
                bn[nn] = *(const bf16x8*)&Bs[wn + nn * 16 + n16][ks * 32 + quad * 8];
#pragma unroll
            for (int mm = 0; mm < RM; ++mm)
#pragma unroll
                for (int nn = 0; nn < RN; ++nn)
                    acc[mm][nn] = __builtin_amdgcn_mfma_f32_16x16x32_bf16(
                        am[mm], bn[nn], acc[mm][nn], 0, 0, 0);
        }
    }

    __syncthreads();   // all LDS frag reads done before Cs aliases As/Bs

    // --- epilogue: acc -> LDS bf16 tile (C^T layout: Cs[n][m]) ---
#pragma unroll
    for (int nn = 0; nn < RN; ++nn) {
        int n = wn + nn * 16 + n16;
#pragma unroll
        for (int mm = 0; mm < RM; ++mm) {
            int m = wm + mm * 16 + quad * 4;
            f32x4 a = acc[mm][nn];
            ushort4 o = make_ushort4(f2bf(a[0]), f2bf(a[1]), f2bf(a[2]), f2bf(a[3]));
            *(ushort4*)&Cs[n][m] = o;
        }
    }
    __syncthreads();

    // --- coalesced store: row n = BM shorts contiguous, uint4 chunks ---
    const int CHUNKS = BM * 2 / 16;
    const int RPP = 256 / CHUNKS;
    const int row = tid / CHUNKS, ch = tid % CHUNKS;
#pragma unroll
    for (int s = 0; s < BN / RPP; ++s) {
        int n = row + s * RPP;
        *(uint4*)(Ct + (size_t)(n0 + n) * 8192 + m0 + ch * 8) =
            *(const uint4*)&Cs[n][ch * 8];
    }

    // --- fused f1/f2 (one head resident: BN==128) ---
    if (DOF) {
        const int mloc = tid & 63, fq = tid >> 6;
        const float* az = aV + blockIdx.y * 256;
        float s1 = 0.f, s2 = 0.f;
#pragma unroll 8
        for (int k = 0; k < 32; ++k) {
            int f = fq * 32 + k;
            float h = bfs(Cs[f][mloc]);
            s1 += h * az[f];
            s2 += h * az[128 + f];
        }
        *(float2*)&redf[(fq * 64 + mloc) * 2] = make_float2(s1, s2);
        __syncthreads();
        if (tid < 64) {
            float a1 = redf[tid * 2]       + redf[(64 + tid) * 2]
                     + redf[(128 + tid) * 2] + redf[(192 + tid) * 2];
            float a2 = redf[tid * 2 + 1]       + redf[(64 + tid) * 2 + 1]
                     + redf[(128 + tid) * 2 + 1] + redf[(192 + tid) * 2 + 1];
            f1g[(size_t)blockIdx.y * 8192 + m0 + tid] = a1;
            f2g[(size_t)blockIdx.y * 8192 + m0 + tid] = a2;
        }
    }
}

// ---------------------------------------------------------------------------
// MFMA attention (layer 1, R9-verified): exp-free p = max(Ai*u, A2i*v),
// double-buffered JT=64 LDS tiles, lsum via ones-column MFMA. XCD-aware
// grid (8=hy, 8=ibx, 8=bz) so same-slice blocks share an XCD L2.
// ---------------------------------------------------------------------------
template <int NI>
__global__ __launch_bounds__(256) void attn4(
    const unsigned short* __restrict__ hT, const float* __restrict__ f1g,
    const float* __restrict__ f2g, unsigned short* __restrict__ outb)
{
    const int N = 1024, JT = 64, JP = 72;
    __shared__ __align__(16) unsigned short hls[2][128][JP];
    __shared__ float ul[1024], vl[1024];
    __shared__ float wred[4];

    const int tid = threadIdx.x;
    const int w = tid >> 6, lane = tid & 63;
    const int n16 = lane & 15, quad = lane >> 4;
    const int hy = blockIdx.x;
    const int bz = blockIdx.z;
    const int ibx = blockIdx.y;
    const int hb = hy * 8 + bz;
    const int ITILE = 64 * NI;
    const int iw0 = ibx * ITILE + w * (16 * NI);

    // u/v tables + block max of f2L
    {
        int j4 = tid * 4;
        float4 fv = *(const float4*)(f2g + (size_t)hb * N + j4);
        fv.x *= LOG2E; fv.y *= LOG2E; fv.z *= LOG2E; fv.w *= LOG2E;
        float m4 = fmaxf(fmaxf(fv.x, fv.y), fmaxf(fv.z, fv.w));
#pragma unroll
        for (int off = 32; off; off >>= 1) m4 = fmaxf(m4, __shfl_xor(m4, off));
        if (lane == 0) wred[w] = m4;
        float4 uu, vv;
        uu.x = __builtin_amdgcn_exp2f(fv.x); vv.x = __builtin_amdgcn_exp2f(ALPHA * fv.x);
        uu.y = __builtin_amdgcn_exp2f(fv.y); vv.y = __builtin_amdgcn_exp2f(ALPHA * fv.y);
        uu.z = __builtin_amdgcn_exp2f(fv.z); vv.z = __builtin_amdgcn_exp2f(ALPHA * fv.z);
        uu.w = __builtin_amdgcn_exp2f(fv.w); vv.w = __builtin_amdgcn_exp2f(ALPHA * fv.w);
        *(float4*)&ul[j4] = uu;
        *(float4*)&vl[j4] = vv;
    }

    float f1L[NI];
#pragma unroll
    for (int ii = 0; ii < NI; ++ii)
        f1L[ii] = f1g[(size_t)hb * N + iw0 + ii * 16 + n16] * LOG2E;

    const unsigned short* gsrc = hT + (size_t)hy * 128 * 8192 + bz * 1024;
    const int sf = tid >> 3, sj = (tid & 7) * 8;

    bf16x8 stg[4];
#pragma unroll
    for (int s = 0; s < 4; ++s)
        stg[s] = *(const bf16x8*)(gsrc + (size_t)(sf + 32 * s) * 8192 + sj);

    __syncthreads();   // ul/vl/wred visible
    const float f2mL = fmaxf(fmaxf(wred[0], wred[1]), fmaxf(wred[2], wred[3]));
    float Ai[NI], A2i[NI];
#pragma unroll
    for (int ii = 0; ii < NI; ++ii) {
        float s = f1L[ii] + f2mL;
        float mc = fmaxf(s, ALPHA * s);
        Ai[ii]  = __builtin_amdgcn_exp2f(f1L[ii] - mc);
        A2i[ii] = __builtin_amdgcn_exp2f(ALPHA * f1L[ii] - mc);
    }

    f32x4 acc[NI][8], accl[NI];
#pragma unroll
    for (int ii = 0; ii < NI; ++ii) {
        accl[ii] = (f32x4){0.f, 0.f, 0.f, 0.f};
#pragma unroll
        for (int t = 0; t < 8; ++t) acc[ii][t] = (f32x4){0.f, 0.f, 0.f, 0.f};
    }
    bf16x8 ones;
    { union { bf16x8 v; unsigned u[4]; } o;
      o.u[0] = o.u[1] = o.u[2] = o.u[3] = 0x3F803F80u; ones = o.v; }

    // stage tile 0 into buf 0
#pragma unroll
    for (int s = 0; s < 4; ++s)
        *(bf16x8*)&hls[0][sf + 32 * s][sj] = stg[s];
    __syncthreads();

    for (int jt = 0; jt < N / JT; ++jt) {
        const int cur = jt & 1;
        if (jt + 1 < N / JT) {
            int j0n = (jt + 1) * JT;
#pragma unroll
            for (int s = 0; s < 4; ++s)
                stg[s] = *(const bf16x8*)(gsrc + (size_t)(sf + 32 * s) * 8192 + j0n + sj);
        }
        const int j0 = jt * JT;
#pragma unroll
        for (int kk = 0; kk < 2; ++kk) {
            const int jb = j0 + kk * 32 + quad * 8;
            float4 u0 = *(const float4*)&ul[jb], u1 = *(const float4*)&ul[jb + 4];
            float4 v0 = *(const float4*)&vl[jb], v1 = *(const float4*)&vl[jb + 4];
            float uj[8] = {u0.x, u0.y, u0.z, u0.w, u1.x, u1.y, u1.z, u1.w};
            float vj[8] = {v0.x, v0.y, v0.z, v0.w, v1.x, v1.y, v1.z, v1.w};

            bf16x8 afr[NI];
#pragma unroll
            for (int ii = 0; ii < NI; ++ii) {
                union { bf16x8 v; unsigned u[4]; } cvt;
#pragma unroll
                for (int q = 0; q < 4; ++q) {
                    float p0 = fmaxf(Ai[ii] * uj[2 * q],     A2i[ii] * vj[2 * q]);
                    float p1 = fmaxf(Ai[ii] * uj[2 * q + 1], A2i[ii] * vj[2 * q + 1]);
                    cvt.u[q] = pkbf_rhu(p0, p1);
                }
                afr[ii] = cvt.v;
            }
#pragma unroll
            for (int t = 0; t < 8; ++t) {
                bf16x8 bfr = *(const bf16x8*)&hls[cur][t * 16 + n16][kk * 32 + quad * 8];
#pragma unroll
                for (int ii = 0; ii < NI; ++ii)
                    acc[ii][t] = __builtin_amdgcn_mfma_f32_16x16x32_bf16(
                        afr[ii], bfr, acc[ii][t], 0, 0, 0);
            }
#pragma unroll
            for (int ii = 0; ii < NI; ++ii)
                accl[ii] = __builtin_amdgcn_mfma_f32_16x16x32_bf16(
                    afr[ii], ones, accl[ii], 0, 0, 0);
        }
        if (jt + 1 < N / JT) {
#pragma unroll
            for (int s = 0; s < 4; ++s)
                *(bf16x8*)&hls[1 - cur][sf + 32 * s][sj] = stg[s];
        }
        __syncthreads();
    }

    // epilogue: C/D layout col=lane&15 (f), row=quad*4+reg (i); lsum in accl
#pragma unroll
    for (int ii = 0; ii < NI; ++ii) {
#pragma unroll
        for (int r = 0; r < 4; ++r) {
            float inv = 1.f / accl[ii][r];
            int i = iw0 + ii * 16 + quad * 4 + r;
#pragma unroll
            for (int t = 0; t < 8; ++t) {
                float tv = acc[ii][t][r] * inv;
                tv = elu1(tv);
                outb[(size_t)(bz * 1024 + i) * 1024 + hy * 128 + t * 16 + n16] = f2bf(tv);
            }
        }
    }
}

// ---------------------------------------------------------------------------
// attn6 (layer 2): attn4 body + in-block f1/f2 computation (replaces the
// fdot3 node). Phase A: each thread computes a1/a2 dots for 4 columns of the
// slice from h2T (coalesced uint2 loads, ao reads are wave-uniform s_loads);
// f2L -> ul (temp), f1 for this block's 64 i -> f1loc. Tile-0 global
// prefetch issued before phase A to overlap. grid (8=bz, 16=ibx).
// ---------------------------------------------------------------------------
__global__ __launch_bounds__(256) void attn6(
    const unsigned short* __restrict__ hT, const float* __restrict__ ao,
    float* __restrict__ outf)
{
    const int N = 1024, JT = 64, JP = 72;
    __shared__ __align__(16) unsigned short hls[2][128][JP];
    __shared__ float ul[1024], vl[1024];
    __shared__ float wred[4];
    __shared__ float f1loc[64];

    const int tid = threadIdx.x;
    const int w = tid >> 6, lane = tid & 63;
    const int n16 = lane & 15, quad = lane >> 4;
    const int bz = blockIdx.x;
    const int ibx = blockIdx.y;
    const int iw0 = ibx * 64 + w * 16;

    const unsigned short* gsrc = hT + bz * 1024;
    const int sf = tid >> 3, sj = (tid & 7) * 8;

    // issue tile-0 staging loads first (in flight during phase A)
    bf16x8 stg[4];
#pragma unroll
    for (int s = 0; s < 4; ++s)
        stg[s] = *(const bf16x8*)(gsrc + (size_t)(sf + 32 * s) * 8192 + sj);

    // --- Phase A: f1/f2 dots, 4 columns per thread ---
    {
        const int c0 = tid * 4;
        const unsigned short* colp = gsrc + c0;
        float s1[4] = {}, s2[4] = {};
#pragma unroll 8
        for (int f = 0; f < 128; ++f) {
            uint2 hv = *(const uint2*)(colp + (size_t)f * 8192);
            float a1 = ao[f], a2 = ao[128 + f];
            float h0 = bflo(hv.x), h1 = bfhi(hv.x), h2 = bflo(hv.y), h3 = bfhi(hv.y);
            s1[0] += h0 * a1; s1[1] += h1 * a1; s1[2] += h2 * a1; s1[3] += h3 * a1;
            s2[0] += h0 * a2; s2[1] += h1 * a2; s2[2] += h2 * a2; s2[3] += h3 * a2;
        }
        float4 f2s = make_float4(s2[0] * LOG2E, s2[1] * LOG2E,
                                 s2[2] * LOG2E, s2[3] * LOG2E);
        *(float4*)&ul[c0] = f2s;                      // temp: raw scaled f2L
        if ((c0 >> 6) == ibx)
            *(float4*)&f1loc[c0 & 63] = make_float4(s1[0], s1[1], s1[2], s1[3]);
        float m4 = fmaxf(fmaxf(f2s.x, f2s.y), fmaxf(f2s.z, f2s.w));
#pragma unroll
        for (int off = 32; off; off >>= 1) m4 = fmaxf(m4, __shfl_xor(m4, off));
        if (lane == 0) wred[w] = m4;
    }
    __syncthreads();   // ul(raw)/f1loc/wred visible

    // convert ul(raw) -> exp2 tables (each thread rewrites only its own slots)
    {
        const int c0 = tid * 4;
        float4 fv = *(const float4*)&ul[c0];
        float4 uu, vv;
        uu.x = __builtin_amdgcn_exp2f(fv.x); vv.x = __builtin_amdgcn_exp2f(ALPHA * fv.x);
        uu.y = __builtin_amdgcn_exp2f(fv.y); vv.y = __builtin_amdgcn_exp2f(ALPHA * fv.y);
        uu.z = __builtin_amdgcn_exp2f(fv.z); vv.z = __builtin_amdgcn_exp2f(ALPHA * fv.z);
        uu.w = __builtin_amdgcn_exp2f(fv.w); vv.w = __builtin_amdgcn_exp2f(ALPHA * fv.w);
        *(float4*)&ul[c0] = uu;
        *(float4*)&vl[c0] = vv;
    }

    const float f2mL = fmaxf(fmaxf(wred[0], wred[1]), fmaxf(wred[2], wred[3]));
    const float f1L = f1loc[w * 16 + n16] * LOG2E;
    float Ai, A2i;
    {
        float s = f1L + f2mL;
        float mc = fmaxf(s, ALPHA * s);
        Ai  = __builtin_amdgcn_exp2f(f1L - mc);
        A2i = __builtin_amdgcn_exp2f(ALPHA * f1L - mc);
    }

    f32x4 acc[8], accl;
    accl = (f32x4){0.f, 0.f, 0.f, 0.f};
#pragma unroll
    for (int t = 0; t < 8; ++t) acc[t] = (f32x4){0.f, 0.f, 0.f, 0.f};
    bf16x8 ones;
    { union { bf16x8 v; unsigned u[4]; } o;
      o.u[0] = o.u[1] = o.u[2] = o.u[3] = 0x3F803F80u; ones = o.v; }

    // stage tile 0 into buf 0
#pragma unroll
    for (int s = 0; s < 4; ++s)
        *(bf16x8*)&hls[0][sf + 32 * s][sj] = stg[s];
    __syncthreads();   // tile 0 + exp2'd ul/vl visible

    for (int jt = 0; jt < N / JT; ++jt) {
        const int cur = jt & 1;
        if (jt + 1 < N / JT) {
            int j0n = (jt + 1) * JT;
#pragma unroll
            for (int s = 0; s < 4; ++s)
                stg[s] = *(const bf16x8*)(gsrc + (size_t)(sf + 32 * s) * 8192 + j0n + sj);
        }
        const int j0 = jt * JT;
#pragma unroll
        for (int kk = 0; kk < 2; ++kk) {
            const int jb = j0 + kk * 32 + quad * 8;
            float4 u0 = *(const float4*)&ul[jb], u1 = *(const float4*)&ul[jb + 4];
            float4 v0 = *(const float4*)&vl[jb], v1 = *(const float4*)&vl[jb + 4];
            float uj[8] = {u0.x, u0.y, u0.z, u0.w, u1.x, u1.y, u1.z, u1.w};
            float vj[8] = {v0.x, v0.y, v0.z, v0.w, v1.x, v1.y, v1.z, v1.w};

            bf16x8 afr;
            {
                union { bf16x8 v; unsigned u[4]; } cvt;
#pragma unroll
                for (int q = 0; q < 4; ++q) {
                    float p0 = fmaxf(Ai * uj[2 * q],     A2i * vj[2 * q]);
                    float p1 = fmaxf(Ai * uj[2 * q + 1], A2i * vj[2 * q + 1]);
                    cvt.u[q] = pkbf_rhu(p0, p1);
                }
                afr = cvt.v;
            }
#pragma unroll
            for (int t = 0; t < 8; ++t) {
                bf16x8 bfr = *(const bf16x8*)&hls[cur][t * 16 + n16][kk * 32 + quad * 8];
                acc[t] = __builtin_amdgcn_mfma_f32_16x16x32_bf16(afr, bfr, acc[t], 0, 0, 0);
            }
            accl = __builtin_amdgcn_mfma_f32_16x16x32_bf16(afr, ones, accl, 0, 0, 0);
        }
        if (jt + 1 < N / JT) {
#pragma unroll
            for (int s = 0; s < 4; ++s)
                *(bf16x8*)&hls[1 - cur][sf + 32 * s][sj] = stg[s];
        }
        __syncthreads();
    }

    // epilogue: double elu, f32 out
#pragma unroll
    for (int r = 0; r < 4; ++r) {
        float inv = 1.f / accl[r];
        int i = iw0 + quad * 4 + r;
#pragma unroll
        for (int t = 0; t < 8; ++t) {
            float tv = acc[t][r] * inv;
            tv = elu1(elu1(tv));
            outf[(size_t)(bz * 1024 + i) * 128 + t * 16 + n16] = tv;
        }
    }
}

// ---------------------------------------------------------------------------
// B=8, N=1024, D=256, H=8, F=128
// ---------------------------------------------------------------------------
extern "C" void kernel_launch(void* const* d_in, const int* in_sizes, int n_in,
                              void* d_out, int out_size, void* d_ws, size_t ws_size,
                              hipStream_t stream)
{
    const float* x  = (const float*)d_in[0];
    const float* Wh = (const float*)d_in[2];
    const float* ah = (const float*)d_in[3];
    const float* Wo = (const float*)d_in[4];
    const float* ao = (const float*)d_in[5];
    float* out = (float*)d_out;

    unsigned short* WhT = (unsigned short*)d_ws;       // [1024][256]
    unsigned short* WoT = WhT + 262144;                // [128][1024]
    unsigned short* h1T = WoT + 131072;                // [8][128][8192]
    unsigned short* xcb = h1T + 8388608;               // [8192][1024]
    unsigned short* h2T = xcb + 8388608;               // [128][8192]
    float* f1a  = (float*)(h2T + 1048576);             // [8][8192]
    float* f2a  = f1a + 65536;                         // [8][8192]

    // prep: both weight transposes in one launch
    cvt_w_all<<<dim3(16, 2, 9), 256, 0, stream>>>(Wh, Wo, WhT, WoT);

    // Layer 1: fused x-convert + GEMM + f1/f2 epilogue
    gemm_t<64, 128, 32, 64, 1, 1><<<dim3(128, 8), 256, 0, stream>>>(
        x, WhT, h1T, 256, ah, f1a, f2a);
    attn4<2><<<dim3(8, 8, 8), 256, 0, stream>>>(h1T, f1a, f2a, xcb);

    // Layer 2: GEMM + attn with in-block f1/f2 (fdot node deleted)
    gemm_t<64, 64, 32, 32, 0, 0><<<dim3(128, 2), 256, 0, stream>>>(
        xcb, WoT, h2T, 1024, nullptr, nullptr, nullptr);
    attn6<<<dim3(8, 16), 256, 0, stream>>>(h2T, ao, out);
}

// Round 14
// 174.102 us; speedup vs baseline: 2.6197x; 1.0311x over previous
//
#include <hip/hip_runtime.h>
#include <math.h>

#define ALPHA 0.2f
#define LOG2E 1.44269504089f

typedef __attribute__((ext_vector_type(8))) short bf16x8;
typedef __attribute__((ext_vector_type(4))) float f32x4;

__device__ __forceinline__ float elu1(float x)  { return x > 0.f ? x : (__expf(x) - 1.f); }

// round-to-nearest-even f32 -> bf16 (finite values only)
__device__ __forceinline__ unsigned short f2bf(float x) {
    unsigned u = __float_as_uint(x);
    return (unsigned short)((u + 0x7fffu + ((u >> 16) & 1u)) >> 16);
}
__device__ __forceinline__ unsigned pkbf16(float a, float b) {
    return (unsigned)f2bf(a) | ((unsigned)f2bf(b) << 16);
}
__device__ __forceinline__ float bflo(unsigned v) { return __uint_as_float(v << 16); }
__device__ __forceinline__ float bfhi(unsigned v) { return __uint_as_float(v & 0xffff0000u); }
__device__ __forceinline__ float bfs(unsigned short v) { return __uint_as_float((unsigned)v << 16); }
// round-half-up pack (a->lo, b->hi) via single v_perm on bias-added bits
__device__ __forceinline__ unsigned pkbf_rhu(float a, float b) {
    unsigned ua = __float_as_uint(a) + 0x8000u;
    unsigned ub = __float_as_uint(b) + 0x8000u;
    return __builtin_amdgcn_perm(ub, ua, 0x07060302u);
}

// ---------------------------------------------------------------------------
// Prep (single launch): W [z][K][128] f32 -> WT [z][128][K] bf16, LDS 64x64
// tile transpose. z<8: Wh (K=256); z==8: Wo (K=1024). grid (16, 2, 9).
// ---------------------------------------------------------------------------
__global__ __launch_bounds__(256) void cvt_w_all(
    const float* __restrict__ Wh, const float* __restrict__ Wo,
    unsigned short* __restrict__ WhT, unsigned short* __restrict__ WoT)
{
    const int z = blockIdx.z;
    const int K = (z < 8) ? 256 : 1024;
    if (blockIdx.x * 64 >= K) return;
    const float* in = (z < 8) ? (Wh + (size_t)z * K * 128) : Wo;
    unsigned short* out = (z < 8) ? (WhT + (size_t)z * 128 * K) : WoT;

    __shared__ float T[64][65];
    const int tid = threadIdx.x;
    const int k0 = blockIdx.x * 64, n0 = blockIdx.y * 64;

    const int kr = tid >> 4, nc = (tid & 15) * 4;
#pragma unroll
    for (int s = 0; s < 4; ++s) {
        float4 v = *(const float4*)(in + (size_t)(k0 + kr + s * 16) * 128 + n0 + nc);
        T[kr + s * 16][nc]     = v.x;
        T[kr + s * 16][nc + 1] = v.y;
        T[kr + s * 16][nc + 2] = v.z;
        T[kr + s * 16][nc + 3] = v.w;
    }
    __syncthreads();
    const int nr0 = tid >> 3, kc = (tid & 7) * 8;
#pragma unroll
    for (int s = 0; s < 2; ++s) {
        int nr = nr0 + s * 32;
        unsigned pk[4];
#pragma unroll
        for (int q = 0; q < 4; ++q)
            pk[q] = pkbf16(T[kc + 2 * q][nr], T[kc + 2 * q + 1][nr]);
        *(uint4*)(out + (size_t)(n0 + nr) * K + k0 + kc) = make_uint4(pk[0], pk[1], pk[2], pk[3]);
    }
}

// ---------------------------------------------------------------------------
// LDS-staged bf16 MFMA GEMM with transposed C store.
// AF32=1: A is f32 (x input), converted to bf16 during LDS staging.
// C^T staged via LDS aliased over As/Bs -> coalesced uint4 stores.
// DOF=1 (BN==128): fused f1/f2 head dot-products from resident C^T tile.
// ---------------------------------------------------------------------------
template <int BM, int BN, int WM, int WN, int DOF, int AF32>
__global__ __launch_bounds__(256) void gemm_t(
    const void* __restrict__ Avp, const unsigned short* __restrict__ Bt,
    unsigned short* __restrict__ Ct, int K,
    const float* __restrict__ aV, float* __restrict__ f1g, float* __restrict__ f2g)
{
    const int RM = WM / 16, RN = WN / 16;
    const int NCA = BM * 8 / 256, NCB = BN * 8 / 256;
    __shared__ __align__(16) unsigned short SAB[(BM + BN) * 72];
    unsigned short (*As)[72] = (unsigned short(*)[72])SAB;
    unsigned short (*Bs)[72] = (unsigned short(*)[72])(SAB + BM * 72);
    unsigned short (*Cs)[BM + 8] = (unsigned short(*)[BM + 8])SAB;   // alias
    float* redf = (float*)(SAB + BN * (BM + 8));                     // after Cs

    const int tid = threadIdx.x;
    const int w = tid >> 6, lane = tid & 63;
    const int n16 = lane & 15, quad = lane >> 4;
    const int WX = BM / WM;
    const int wm = (w % WX) * WM, wn = (w / WX) * WN;
    const int m0 = blockIdx.x * BM, n0 = blockIdx.y * BN;

    const float* Af = (const float*)Avp;
    const unsigned short* Ab = (const unsigned short*)Avp;
    const int ar = tid >> 2, akc = (tid & 3) * 16;

    f32x4 acc[RM][RN];
#pragma unroll
    for (int mm = 0; mm < RM; ++mm)
#pragma unroll
        for (int nn = 0; nn < RN; ++nn) acc[mm][nn] = (f32x4){0.f, 0.f, 0.f, 0.f};

    uint4 ra[NCA], rb[NCB];
    float4 raf[4];
    if (AF32) {
#pragma unroll
        for (int j = 0; j < 4; ++j)
            raf[j] = *(const float4*)(Af + (size_t)(m0 + ar) * K + akc + 4 * j);
    } else {
#pragma unroll
        for (int i = 0; i < NCA; ++i) {
            int c = tid * NCA + i, r = c >> 3, cc = (c & 7) * 8;
            ra[i] = *(const uint4*)(Ab + (size_t)(m0 + r) * K + cc);
        }
    }
#pragma unroll
    for (int i = 0; i < NCB; ++i) {
        int c = tid * NCB + i, r = c >> 3, cc = (c & 7) * 8;
        rb[i] = *(const uint4*)(Bt + (size_t)(n0 + r) * K + cc);
    }

    const int nk = K >> 6;
    for (int kt = 0; kt < nk; ++kt) {
        __syncthreads();
        if (AF32) {
            uint4 lo = make_uint4(pkbf16(raf[0].x, raf[0].y), pkbf16(raf[0].z, raf[0].w),
                                  pkbf16(raf[1].x, raf[1].y), pkbf16(raf[1].z, raf[1].w));
            uint4 hi = make_uint4(pkbf16(raf[2].x, raf[2].y), pkbf16(raf[2].z, raf[2].w),
                                  pkbf16(raf[3].x, raf[3].y), pkbf16(raf[3].z, raf[3].w));
            *(uint4*)&As[ar][akc]     = lo;
            *(uint4*)&As[ar][akc + 8] = hi;
        } else {
#pragma unroll
            for (int i = 0; i < NCA; ++i) {
                int c = tid * NCA + i, r = c >> 3, cc = (c & 7) * 8;
                *(uint4*)&As[r][cc] = ra[i];
            }
        }
#pragma unroll
        for (int i = 0; i < NCB; ++i) {
            int c = tid * NCB + i, r = c >> 3, cc = (c & 7) * 8;
            *(uint4*)&Bs[r][cc] = rb[i];
        }
        __syncthreads();
        if (kt + 1 < nk) {
            int k0 = (kt + 1) * 64;
            if (AF32) {
#pragma unroll
                for (int j = 0; j < 4; ++j)
                    raf[j] = *(const float4*)(Af + (size_t)(m0 + ar) * K + k0 + akc + 4 * j);
            } else {
#pragma unroll
                for (int i = 0; i < NCA; ++i) {
                    int c = tid * NCA + i, r = c >> 3, cc = (c & 7) * 8;
                    ra[i] = *(const uint4*)(Ab + (size_t)(m0 + r) * K + k0 + cc);
                }
            }
#pragma unroll
            for (int i = 0; i < NCB; ++i) {
                int c = tid * NCB + i, r = c >> 3, cc = (c & 7) * 8;
                rb[i] = *(const uint4*)(Bt + (size_t)(n0 + r) * K + k0 + cc);
            }
        }
#pragma unroll
        for (int ks = 0; ks < 2; ++ks) {
            bf16x8 am[RM], bn[RN];
#pragma unroll
            for (int mm = 0; mm < RM; ++mm)
                am[mm] = *(const bf16x8*)&As[wm + mm * 16 + n16][ks * 32 + quad * 8];
#pragma unroll
            for (int nn = 0; nn < RN; ++nn)
                bn[nn] = *(const bf16x8*)&Bs[wn + nn * 16 + n16][ks * 32 + quad * 8];
#pragma unroll
            for (int mm = 0; mm < RM; ++mm)
#pragma unroll
                for (int nn = 0; nn < RN; ++nn)
                    acc[mm][nn] = __builtin_amdgcn_mfma_f32_16x16x32_bf16(
                        am[mm], bn[nn], acc[mm][nn], 0, 0, 0);
        }
    }

    __syncthreads();   // all LDS frag reads done before Cs aliases As/Bs

    // --- epilogue: acc -> LDS bf16 tile (C^T layout: Cs[n][m]) ---
#pragma unroll
    for (int nn = 0; nn < RN; ++nn) {
        int n = wn + nn * 16 + n16;
#pragma unroll
        for (int mm = 0; mm < RM; ++mm) {
            int m = wm + mm * 16 + quad * 4;
            f32x4 a = acc[mm][nn];
            ushort4 o = make_ushort4(f2bf(a[0]), f2bf(a[1]), f2bf(a[2]), f2bf(a[3]));
            *(ushort4*)&Cs[n][m] = o;
        }
    }
    __syncthreads();

    // --- coalesced store: row n = BM shorts contiguous, uint4 chunks ---
    const int CHUNKS = BM * 2 / 16;
    const int RPP = 256 / CHUNKS;
    const int row = tid / CHUNKS, ch = tid % CHUNKS;
#pragma unroll
    for (int s = 0; s < BN / RPP; ++s) {
        int n = row + s * RPP;
        *(uint4*)(Ct + (size_t)(n0 + n) * 8192 + m0 + ch * 8) =
            *(const uint4*)&Cs[n][ch * 8];
    }

    // --- fused f1/f2 (one head resident: BN==128) ---
    if (DOF) {
        const int mloc = tid & 63, fq = tid >> 6;
        const float* az = aV + blockIdx.y * 256;
        float s1 = 0.f, s2 = 0.f;
#pragma unroll 8
        for (int k = 0; k < 32; ++k) {
            int f = fq * 32 + k;
            float h = bfs(Cs[f][mloc]);
            s1 += h * az[f];
            s2 += h * az[128 + f];
        }
        *(float2*)&redf[(fq * 64 + mloc) * 2] = make_float2(s1, s2);
        __syncthreads();
        if (tid < 64) {
            float a1 = redf[tid * 2]       + redf[(64 + tid) * 2]
                     + redf[(128 + tid) * 2] + redf[(192 + tid) * 2];
            float a2 = redf[tid * 2 + 1]       + redf[(64 + tid) * 2 + 1]
                     + redf[(128 + tid) * 2 + 1] + redf[(192 + tid) * 2 + 1];
            f1g[(size_t)blockIdx.y * 8192 + m0 + tid] = a1;
            f2g[(size_t)blockIdx.y * 8192 + m0 + tid] = a2;
        }
    }
}

// ---------------------------------------------------------------------------
// f1/f2 from transposed bf16 hT[z][f][8192] (layer-2 only). grid (64, Z).
// ---------------------------------------------------------------------------
__global__ __launch_bounds__(256) void fdot3(
    const unsigned short* __restrict__ hT, const float* __restrict__ a,
    float* __restrict__ f1, float* __restrict__ f2)
{
    __shared__ float4 red[4][64];
    const int tid = threadIdx.x;
    const int fq = tid >> 6, tm = tid & 63;
    const int z = blockIdx.y;
    const int m0 = blockIdx.x * 128 + tm * 2;
    const float* az = a + z * 256;

    float s10 = 0.f, s11 = 0.f, s20 = 0.f, s21 = 0.f;
#pragma unroll 8
    for (int f = fq * 32; f < fq * 32 + 32; ++f) {
        unsigned u = *(const unsigned*)(hT + ((size_t)(z * 128 + f) << 13) + m0);
        float a1 = az[f], a2 = az[128 + f];
        float h0 = bflo(u), h1 = bfhi(u);
        s10 += h0 * a1; s11 += h1 * a1;
        s20 += h0 * a2; s21 += h1 * a2;
    }
    red[fq][tm] = make_float4(s10, s11, s20, s21);
    __syncthreads();
    if (tid < 64) {
        float4 r0 = red[0][tid], r1 = red[1][tid], r2 = red[2][tid], r3 = red[3][tid];
        size_t o = ((size_t)z << 13) + blockIdx.x * 128 + tid * 2;
        *(float2*)(f1 + o) = make_float2(r0.x + r1.x + r2.x + r3.x,
                                         r0.y + r1.y + r2.y + r3.y);
        *(float2*)(f2 + o) = make_float2(r0.z + r1.z + r2.z + r3.z,
                                         r0.w + r1.w + r2.w + r3.w);
    }
}

// ---------------------------------------------------------------------------
// MFMA attention v7 — Ai-cancelled exp-free inner loop + dbuf JT=64 tiles.
// Softmax is invariant to per-row scale, so feed q_ij = max(u_j, r_i*v_j):
//   u = exp2(f2L - f2mL) <= 1,  v = exp2(a*(f2L - f2mL)) <= 1,
//   r_i = exp2((a-1)*(f1L + f2mL));  old Ai factor cancels vs ones-MFMA lsum.
// Inner p-build: 1 mul + 1 max per element (was 2 mul + 1 max).
// One barrier/tile (double-buffered LDS); lsum via ones-column MFMA.
// XCD-aware grid: slice coord on blockIdx.x.
// L1 (OUTBF=1): grid (8=hy, 8, 8=bz); L2 (OUTBF=0): grid (8=bz, 16, 1).
// ---------------------------------------------------------------------------
template <int NI, int OUTBF>
__global__ __launch_bounds__(256) void attn4(
    const unsigned short* __restrict__ hT, const float* __restrict__ f1g,
    const float* __restrict__ f2g, float* __restrict__ outf,
    unsigned short* __restrict__ outb, int elu2)
{
    const int N = 1024, JT = 64, JP = 72;
    __shared__ __align__(16) unsigned short hls[2][128][JP];
    __shared__ float ul[1024], vl[1024];
    __shared__ float wred[4];

    const int tid = threadIdx.x;
    const int w = tid >> 6, lane = tid & 63;
    const int n16 = lane & 15, quad = lane >> 4;
    const int hy = OUTBF ? blockIdx.x : 0;
    const int bz = OUTBF ? blockIdx.z : blockIdx.x;
    const int ibx = blockIdx.y;
    const int hb = hy * 8 + bz;
    const int ITILE = 64 * NI;
    const int iw0 = ibx * ITILE + w * (16 * NI);

    // raw f2L -> ul (temp) + block max
    const int j4 = tid * 4;
    {
        float4 fv = *(const float4*)(f2g + (size_t)hb * N + j4);
        fv.x *= LOG2E; fv.y *= LOG2E; fv.z *= LOG2E; fv.w *= LOG2E;
        *(float4*)&ul[j4] = fv;
        float m4 = fmaxf(fmaxf(fv.x, fv.y), fmaxf(fv.z, fv.w));
#pragma unroll
        for (int off = 32; off; off >>= 1) m4 = fmaxf(m4, __shfl_xor(m4, off));
        if (lane == 0) wred[w] = m4;
    }

    float f1L[NI];
#pragma unroll
    for (int ii = 0; ii < NI; ++ii)
        f1L[ii] = f1g[(size_t)hb * N + iw0 + ii * 16 + n16] * LOG2E;

    const unsigned short* gsrc = hT + (size_t)hy * 128 * 8192 + bz * 1024;
    const int sf = tid >> 3, sj = (tid & 7) * 8;

    bf16x8 stg[4];
#pragma unroll
    for (int s = 0; s < 4; ++s)
        stg[s] = *(const bf16x8*)(gsrc + (size_t)(sf + 32 * s) * 8192 + sj);

    __syncthreads();   // ul(raw)/wred visible
    const float f2mL = fmaxf(fmaxf(wred[0], wred[1]), fmaxf(wred[2], wred[3]));

    // rewrite own slots: u = exp2(raw - f2mL), v = exp2(a*(raw - f2mL))
    {
        float4 raw = *(const float4*)&ul[j4];
        float4 uu, vv;
        float d0 = raw.x - f2mL, d1 = raw.y - f2mL, d2 = raw.z - f2mL, d3 = raw.w - f2mL;
        uu.x = __builtin_amdgcn_exp2f(d0); vv.x = __builtin_amdgcn_exp2f(ALPHA * d0);
        uu.y = __builtin_amdgcn_exp2f(d1); vv.y = __builtin_amdgcn_exp2f(ALPHA * d1);
        uu.z = __builtin_amdgcn_exp2f(d2); vv.z = __builtin_amdgcn_exp2f(ALPHA * d2);
        uu.w = __builtin_amdgcn_exp2f(d3); vv.w = __builtin_amdgcn_exp2f(ALPHA * d3);
        *(float4*)&ul[j4] = uu;
        *(float4*)&vl[j4] = vv;
    }

    float ri[NI];
#pragma unroll
    for (int ii = 0; ii < NI; ++ii)
        ri[ii] = __builtin_amdgcn_exp2f((ALPHA - 1.f) * (f1L[ii] + f2mL));

    f32x4 acc[NI][8], accl[NI];
#pragma unroll
    for (int ii = 0; ii < NI; ++ii) {
        accl[ii] = (f32x4){0.f, 0.f, 0.f, 0.f};
#pragma unroll
        for (int t = 0; t < 8; ++t) acc[ii][t] = (f32x4){0.f, 0.f, 0.f, 0.f};
    }
    bf16x8 ones;
    { union { bf16x8 v; unsigned u[4]; } o;
      o.u[0] = o.u[1] = o.u[2] = o.u[3] = 0x3F803F80u; ones = o.v; }

    // stage tile 0 into buf 0
#pragma unroll
    for (int s = 0; s < 4; ++s)
        *(bf16x8*)&hls[0][sf + 32 * s][sj] = stg[s];
    __syncthreads();   // tile 0 + rewritten ul/vl visible

    for (int jt = 0; jt < N / JT; ++jt) {
        const int cur = jt & 1;
        if (jt + 1 < N / JT) {
            int j0n = (jt + 1) * JT;
#pragma unroll
            for (int s = 0; s < 4; ++s)
                stg[s] = *(const bf16x8*)(gsrc + (size_t)(sf + 32 * s) * 8192 + j0n + sj);
        }
        const int j0 = jt * JT;
#pragma unroll
        for (int kk = 0; kk < 2; ++kk) {
            const int jb = j0 + kk * 32 + quad * 8;
            float4 u0 = *(const float4*)&ul[jb], u1 = *(const float4*)&ul[jb + 4];
            float4 v0 = *(const float4*)&vl[jb], v1 = *(const float4*)&vl[jb + 4];
            float uj[8] = {u0.x, u0.y, u0.z, u0.w, u1.x, u1.y, u1.z, u1.w};
            float vj[8] = {v0.x, v0.y, v0.z, v0.w, v1.x, v1.y, v1.z, v1.w};

            bf16x8 afr[NI];
#pragma unroll
            for (int ii = 0; ii < NI; ++ii) {
                union { bf16x8 v; unsigned u[4]; } cvt;
#pragma unroll
                for (int q = 0; q < 4; ++q) {
                    float p0 = fmaxf(uj[2 * q],     ri[ii] * vj[2 * q]);
                    float p1 = fmaxf(uj[2 * q + 1], ri[ii] * vj[2 * q + 1]);
                    cvt.u[q] = pkbf_rhu(p0, p1);
                }
                afr[ii] = cvt.v;
            }
#pragma unroll
            for (int t = 0; t < 8; ++t) {
                bf16x8 bfr = *(const bf16x8*)&hls[cur][t * 16 + n16][kk * 32 + quad * 8];
#pragma unroll
                for (int ii = 0; ii < NI; ++ii)
                    acc[ii][t] = __builtin_amdgcn_mfma_f32_16x16x32_bf16(
                        afr[ii], bfr, acc[ii][t], 0, 0, 0);
            }
#pragma unroll
            for (int ii = 0; ii < NI; ++ii)
                accl[ii] = __builtin_amdgcn_mfma_f32_16x16x32_bf16(
                    afr[ii], ones, accl[ii], 0, 0, 0);
        }
        if (jt + 1 < N / JT) {
#pragma unroll
            for (int s = 0; s < 4; ++s)
                *(bf16x8*)&hls[1 - cur][sf + 32 * s][sj] = stg[s];
        }
        __syncthreads();
    }

    // epilogue: C/D layout col=lane&15 (f), row=quad*4+reg (i); lsum in accl
#pragma unroll
    for (int ii = 0; ii < NI; ++ii) {
#pragma unroll
        for (int r = 0; r < 4; ++r) {
            float inv = 1.f / accl[ii][r];
            int i = iw0 + ii * 16 + quad * 4 + r;
#pragma unroll
            for (int t = 0; t < 8; ++t) {
                float tv = acc[ii][t][r] * inv;
                tv = elu1(tv);
                if (OUTBF) {
                    outb[(size_t)(bz * 1024 + i) * 1024 + hy * 128 + t * 16 + n16] = f2bf(tv);
                } else {
                    if (elu2) tv = elu1(tv);
                    outf[(size_t)(bz * 1024 + i) * 128 + t * 16 + n16] = tv;
                }
            }
        }
    }
}

// ---------------------------------------------------------------------------
// B=8, N=1024, D=256, H=8, F=128
// ---------------------------------------------------------------------------
extern "C" void kernel_launch(void* const* d_in, const int* in_sizes, int n_in,
                              void* d_out, int out_size, void* d_ws, size_t ws_size,
                              hipStream_t stream)
{
    const float* x  = (const float*)d_in[0];
    const float* Wh = (const float*)d_in[2];
    const float* ah = (const float*)d_in[3];
    const float* Wo = (const float*)d_in[4];
    const float* ao = (const float*)d_in[5];
    float* out = (float*)d_out;

    unsigned short* WhT = (unsigned short*)d_ws;       // [1024][256]
    unsigned short* WoT = WhT + 262144;                // [128][1024]
    unsigned short* h1T = WoT + 131072;                // [8][128][8192]
    unsigned short* xcb = h1T + 8388608;               // [8192][1024]
    unsigned short* h2T = xcb + 8388608;               // [128][8192]
    float* f1a  = (float*)(h2T + 1048576);             // [8][8192]
    float* f2a  = f1a + 65536;                         // [8][8192]
    float* f1b  = f2a + 65536;                         // [8192]
    float* f2b  = f1b + 8192;                          // [8192]

    // prep: both weight transposes in one launch
    cvt_w_all<<<dim3(16, 2, 9), 256, 0, stream>>>(Wh, Wo, WhT, WoT);

    // Layer 1: fused x-convert + GEMM + f1/f2 epilogue
    gemm_t<64, 128, 32, 64, 1, 1><<<dim3(128, 8), 256, 0, stream>>>(
        x, WhT, h1T, 256, ah, f1a, f2a);
    attn4<2, 1><<<dim3(8, 8, 8), 256, 0, stream>>>(h1T, f1a, f2a, nullptr, xcb, 0);

    // Layer 2
    gemm_t<64, 64, 32, 32, 0, 0><<<dim3(128, 2), 256, 0, stream>>>(
        xcb, WoT, h2T, 1024, nullptr, nullptr, nullptr);
    fdot3<<<dim3(64, 1), 256, 0, stream>>>(h2T, ao, f1b, f2b);
    attn4<1, 0><<<dim3(8, 16, 1), 256, 0, stream>>>(h2T, f1b, f2b, out, nullptr, 1);
}